// Round 1
// baseline (1614.941 us; speedup 1.0000x reference)
//
#include <hip/hip_runtime.h>
#include <math.h>

#define S_ 1024
#define B_ 128
#define F_ 202
#define H_ 100
#define K_ 19
#define FP_ 208   // F padded to multiple of 16B-friendly float4 slices (2 x 104)
#define HP_ 128   // H padded for 8x16 W_out slices; recur uses 2 x 56 = 112

// ---------------------------------------------------------------------------
// Kernel 1: one workgroup per (direction, batch) chain. Fuses:
//   - input projection xp[t+1] = W_ih . x[t+1] + b_ih + b_hh   (pipelined)
//   - recurrence       h[t]    = tanh(xp[t] + W_hh . h[t-1])
//   - partial logits   L[t-1] += W_out[:, dir*100 : dir*100+100] . h[t-1]
// x rows are double-buffered in LDS with a 2-step global->reg->LDS pipeline.
// All weights live in VGPRs (104 + 56 + 16 floats/thread), so
// __launch_bounds__(256,1) is required to allow the register budget.
// ---------------------------------------------------------------------------
__global__ __launch_bounds__(256, 1) void rnn_chain_kernel(
    const float* __restrict__ x,
    const float* __restrict__ Wih_f, const float* __restrict__ Whh_f,
    const float* __restrict__ bih_f, const float* __restrict__ bhh_f,
    const float* __restrict__ Wih_b, const float* __restrict__ Whh_b,
    const float* __restrict__ bih_b, const float* __restrict__ bhh_b,
    const float* __restrict__ Wout,
    float* __restrict__ Lbuf)
{
    const int tid = threadIdx.x;
    const int dir = blockIdx.x >> 7;   // 0 = forward, 1 = backward
    const int b   = blockIdx.x & 127;

    const float* Wih = dir ? Wih_b : Wih_f;
    const float* Whh = dir ? Whh_b : Whh_f;
    const float* bih = dir ? bih_b : bih_f;
    const float* bhh = dir ? bhh_b : bhh_f;

    __shared__ __align__(16) float x_buf[2][FP_];
    __shared__ __align__(16) float xp_buf[2][H_];
    __shared__ __align__(16) float h_buf[2][HP_];

    float wih[104];   // proj slice  (thread pair (2i,2i+1) splits padded-208 f-range)
    float whh[56];    // recur slice (same pair splits padded-112 j-range)
    float wout[16];   // L slice     (8 threads per k split padded-128 j-range)
    float bias = 0.f;

    const int i   = tid >> 1;   // output index for proj/recur (tid < 200)
    const int hf_ = tid & 1;    // which half of the dot product

    if (tid < 200) {
        const int f0 = hf_ * 104;
        #pragma unroll
        for (int q = 0; q < 104; ++q) {
            const int f = f0 + q;
            wih[q] = (f < F_) ? Wih[(size_t)i * F_ + f] : 0.f;
        }
        const int j0 = hf_ * 56;
        #pragma unroll
        for (int q = 0; q < 56; ++q) {
            const int j = j0 + q;
            whh[q] = (j < H_) ? Whh[(size_t)i * H_ + j] : 0.f;
        }
        if (hf_ == 0) bias = bih[i] + bhh[i];
    }
    const int lk = tid >> 3;    // tag k for L phase (tid < 152 = 19*8)
    const int ls = tid & 7;
    if (tid < 152) {
        #pragma unroll
        for (int q = 0; q < 16; ++q) {
            const int j = ls * 16 + q;
            wout[q] = (j < H_) ? Wout[(size_t)lk * (2 * H_) + dir * H_ + j] : 0.f;
        }
    }

    // LDS init: zero pads (never rewritten) + zero initial hidden state
    for (int q = tid; q < FP_; q += 256) { x_buf[0][q] = 0.f; x_buf[1][q] = 0.f; }
    for (int q = tid; q < HP_; q += 256) { h_buf[0][q] = 0.f; h_buf[1][q] = 0.f; }
    __syncthreads();

    // stage x rows for steps 0 and 1 directly
    {
        const int p0 = dir ? (S_ - 1) : 0;
        const int p1 = dir ? (S_ - 2) : 1;
        const float* r0 = x + ((size_t)p0 * B_ + b) * F_;
        const float* r1 = x + ((size_t)p1 * B_ + b) * F_;
        for (int q = tid; q < F_; q += 256) x_buf[0][q] = r0[q];
        for (int q = tid; q < F_; q += 256) x_buf[1][q] = r1[q];
    }
    __syncthreads();

    auto do_proj = [&](int slot) {
        float a0 = 0.f, a1 = 0.f, a2 = 0.f, a3 = 0.f;
        const float* xb = &x_buf[slot][hf_ * 104];
        #pragma unroll
        for (int q = 0; q < 26; ++q) {
            float4 xv = *(const float4*)(xb + q * 4);
            a0 = fmaf(wih[q * 4 + 0], xv.x, a0);
            a1 = fmaf(wih[q * 4 + 1], xv.y, a1);
            a2 = fmaf(wih[q * 4 + 2], xv.z, a2);
            a3 = fmaf(wih[q * 4 + 3], xv.w, a3);
        }
        float acc = (a0 + a1) + (a2 + a3);
        acc += __shfl_xor(acc, 1);
        if (hf_ == 0) xp_buf[slot][i] = acc + bias;
    };

    auto do_L = [&](int slot, int p) {
        float a0 = 0.f, a1 = 0.f, a2 = 0.f, a3 = 0.f;
        const float* hb = &h_buf[slot][ls * 16];
        #pragma unroll
        for (int q = 0; q < 4; ++q) {
            float4 hv = *(const float4*)(hb + q * 4);
            a0 = fmaf(wout[q * 4 + 0], hv.x, a0);
            a1 = fmaf(wout[q * 4 + 1], hv.y, a1);
            a2 = fmaf(wout[q * 4 + 2], hv.z, a2);
            a3 = fmaf(wout[q * 4 + 3], hv.w, a3);
        }
        float acc = (a0 + a1) + (a2 + a3);
        acc += __shfl_xor(acc, 1);
        acc += __shfl_xor(acc, 2);
        acc += __shfl_xor(acc, 4);
        // exactly 2 atomic adds per cell (fwd + bwd) onto zero: deterministic
        if (ls == 0) atomicAdd(&Lbuf[((size_t)p * B_ + b) * K_ + lk], acc);
    };

    // prologue: xp for step 0; preload x[2] into staging regs
    if (tid < 200) do_proj(0);

    float sreg0 = 0.f, sreg1 = 0.f, sreg2 = 0.f, sreg3 = 0.f;
    const int su = tid - 200;   // staging lanes: tid 200..255 cover 56*4 >= 202 floats
    if (su >= 0) {
        const int p2 = dir ? (S_ - 3) : 2;
        const float* r = x + ((size_t)p2 * B_ + b) * F_;
        const int f0 = su * 4;
        sreg0 = (f0 + 0 < F_) ? r[f0 + 0] : 0.f;
        sreg1 = (f0 + 1 < F_) ? r[f0 + 1] : 0.f;
        sreg2 = (f0 + 2 < F_) ? r[f0 + 2] : 0.f;
        sreg3 = (f0 + 3 < F_) ? r[f0 + 3] : 0.f;
    }
    __syncthreads();

    for (int t = 0; t < S_; ++t) {
        const int cur = t & 1;
        const int nxt = cur ^ 1;

        // (1) commit staged x[t+2] (loaded last step) into x_buf[cur]
        if (su >= 0 && t + 2 < S_) {
            const int f0 = su * 4;
            if (f0 + 0 < F_) x_buf[cur][f0 + 0] = sreg0;
            if (f0 + 1 < F_) x_buf[cur][f0 + 1] = sreg1;
            if (f0 + 2 < F_) x_buf[cur][f0 + 2] = sreg2;
            if (f0 + 3 < F_) x_buf[cur][f0 + 3] = sreg3;
        }
        // (2) issue global loads for x[t+3] (one step of latency hiding)
        if (su >= 0 && t + 3 < S_) {
            const int p = dir ? (S_ - 4 - t) : (t + 3);
            const float* r = x + ((size_t)p * B_ + b) * F_;
            const int f0 = su * 4;
            sreg0 = (f0 + 0 < F_) ? r[f0 + 0] : 0.f;
            sreg1 = (f0 + 1 < F_) ? r[f0 + 1] : 0.f;
            sreg2 = (f0 + 2 < F_) ? r[f0 + 2] : 0.f;
            sreg3 = (f0 + 3 < F_) ? r[f0 + 3] : 0.f;
        }
        // (3) recurrence: h[t] = tanh(xp[t] + Whh . h[t-1])
        if (tid < 200) {
            float a0 = 0.f, a1 = 0.f, a2 = 0.f, a3 = 0.f;
            const float* hb = &h_buf[cur][hf_ * 56];
            #pragma unroll
            for (int q = 0; q < 14; ++q) {
                float4 hv = *(const float4*)(hb + q * 4);
                a0 = fmaf(whh[q * 4 + 0], hv.x, a0);
                a1 = fmaf(whh[q * 4 + 1], hv.y, a1);
                a2 = fmaf(whh[q * 4 + 2], hv.z, a2);
                a3 = fmaf(whh[q * 4 + 3], hv.w, a3);
            }
            float acc = (a0 + a1) + (a2 + a3);
            acc += __shfl_xor(acc, 1);
            if (hf_ == 0) {
                float v = acc + xp_buf[cur][i];
                h_buf[nxt][i] = tanhf(v);
            }
        }
        // (4) partial logits for h[t-1] (stable in h_buf[cur] this step)
        if (t >= 1 && tid < 152) {
            const int p = dir ? (S_ - t) : (t - 1);
            do_L(cur, p);
        }
        // (5) projection for step t+1 (independent of h -> hides latency)
        if (t + 1 < S_ && tid < 200) do_proj(nxt);

        __syncthreads();
    }
    // epilogue: logits for the final h (S_ even -> lives in h_buf[0])
    if (tid < 152) {
        const int p = dir ? 0 : (S_ - 1);
        do_L(0, p);
    }
}

// ---------------------------------------------------------------------------
// Kernel 2: softmax + Viterbi along the batch axis (T = B_ = 128 steps),
// one wave per sequence n in [0,1024), 4 sequences per workgroup.
// fp32 op order matches the reference exactly: (score+trans)+e ; start+em ;
// score+end ; argmax keeps the first (lowest-index) maximum.
// ---------------------------------------------------------------------------
__global__ __launch_bounds__(256) void viterbi_kernel(
    const float* __restrict__ Lbuf,
    const float* __restrict__ b_out,
    const float* __restrict__ start_t,
    const float* __restrict__ end_t,
    const float* __restrict__ trans,
    float* __restrict__ out)
{
    const int w    = threadIdx.x >> 6;
    const int lane = threadIdx.x & 63;
    const int n    = blockIdx.x * 4 + w;

    __shared__ float         score_s[4][20];
    __shared__ unsigned char hist_s[4][B_][20];
    __shared__ unsigned char tags_s[4][B_];

    const int kk = (lane < K_) ? lane : 0;
    float tcol[K_];                       // trans[:, k] in registers
    #pragma unroll
    for (int j = 0; j < K_; ++j) tcol[j] = trans[j * K_ + kk];
    const float bko = b_out[kk];
    const float stk = start_t[kk];
    const float enk = end_t[kk];

    const float* Lrow = Lbuf + (size_t)n * B_ * K_;

    // t = 0: score = start + em[0]
    {
        float lg = -1e30f;
        if (lane < K_) lg = Lrow[kk] + bko;
        float m = lg;
        #pragma unroll
        for (int d = 16; d >= 1; d >>= 1) m = fmaxf(m, __shfl_xor(m, d, 32));
        float pp = (lane < K_) ? expf(lg - m) : 0.f;
        float ssum = pp;
        #pragma unroll
        for (int d = 16; d >= 1; d >>= 1) ssum += __shfl_xor(ssum, d, 32);
        if (lane < K_) score_s[w][lane] = stk + pp / ssum;
    }

    for (int t = 1; t < B_; ++t) {
        // emission em[n, t, k] = softmax_k(L + b_out)
        float lg = -1e30f;
        if (lane < K_) lg = Lrow[t * K_ + kk] + bko;
        float m = lg;
        #pragma unroll
        for (int d = 16; d >= 1; d >>= 1) m = fmaxf(m, __shfl_xor(m, d, 32));
        float pp = (lane < K_) ? expf(lg - m) : 0.f;
        float ssum = pp;
        #pragma unroll
        for (int d = 16; d >= 1; d >>= 1) ssum += __shfl_xor(ssum, d, 32);
        const float e = pp / ssum;

        // DP step: max_j (score[j] + trans[j,k]) + e[k], first-index tie-break
        float best = -1e30f; int am = 0;
        #pragma unroll
        for (int j = 0; j < K_; ++j) {
            float v = (score_s[w][j] + tcol[j]) + e;   // same add order as ref
            if (v > best) { best = v; am = j; }
        }
        if (lane < K_) {
            hist_s[w][t][lane] = (unsigned char)am;
            score_s[w][lane]   = best;   // wave-lockstep: all reads precede writes
        }
    }

    if (lane < K_) score_s[w][lane] += enk;

    if (lane == 0) {
        float bestv = score_s[w][0]; int bi = 0;
        for (int j = 1; j < K_; ++j) {
            float v = score_s[w][j];
            if (v > bestv) { bestv = v; bi = j; }
        }
        int tag = bi;
        tags_s[w][B_ - 1] = (unsigned char)tag;
        for (int t = B_ - 2; t >= 0; --t) {
            tag = hist_s[w][t + 1][tag];
            tags_s[w][t] = (unsigned char)tag;
        }
    }
    // coalesced output: 2 floats per lane
    out[(size_t)n * B_ + lane]      = (float)tags_s[w][lane];
    out[(size_t)n * B_ + 64 + lane] = (float)tags_s[w][64 + lane];
}

extern "C" void kernel_launch(void* const* d_in, const int* in_sizes, int n_in,
                              void* d_out, int out_size, void* d_ws, size_t ws_size,
                              hipStream_t stream)
{
    const float* x       = (const float*)d_in[0];
    const float* Wih_f   = (const float*)d_in[1];
    const float* Whh_f   = (const float*)d_in[2];
    const float* bih_f   = (const float*)d_in[3];
    const float* bhh_f   = (const float*)d_in[4];
    const float* Wih_b   = (const float*)d_in[5];
    const float* Whh_b   = (const float*)d_in[6];
    const float* bih_b   = (const float*)d_in[7];
    const float* bhh_b   = (const float*)d_in[8];
    const float* Wout    = (const float*)d_in[9];
    const float* b_out   = (const float*)d_in[10];
    const float* start_t = (const float*)d_in[11];
    const float* end_t   = (const float*)d_in[12];
    const float* trans   = (const float*)d_in[13];

    float* Lbuf = (float*)d_ws;           // (S,B,K) fp32 = ~9.96 MB
    float* out  = (float*)d_out;          // (S,B) fp32 tags

    hipMemsetAsync(Lbuf, 0, (size_t)S_ * B_ * K_ * sizeof(float), stream);

    rnn_chain_kernel<<<dim3(256), dim3(256), 0, stream>>>(
        x, Wih_f, Whh_f, bih_f, bhh_f, Wih_b, Whh_b, bih_b, bhh_b, Wout, Lbuf);

    viterbi_kernel<<<dim3(256), dim3(256), 0, stream>>>(
        Lbuf, b_out, start_t, end_t, trans, out);
}